// Round 5
// baseline (2223.382 us; speedup 1.0000x reference)
//
#include <hip/hip_runtime.h>

#define TLEN  512
#define HID   128
#define RSLOT 32   // ring slots per slice (power of 2)

typedef __attribute__((ext_vector_type(8))) short          bf16x8;
typedef __attribute__((ext_vector_type(4))) float          f32x4;
typedef __attribute__((ext_vector_type(4))) unsigned short u16x4;
typedef unsigned long long u64;

#define LOG2E  1.4426950408889634f
#define LOG2E2 2.8853900817779268f

__device__ __forceinline__ unsigned short f2bf(float f) {
    union { float f; unsigned u; } v; v.f = f;
    unsigned r = v.u + 0x7fffu + ((v.u >> 16) & 1u);   // RNE
    return (unsigned short)(r >> 16);
}

// xs pre-scaled by log2(e): sigmoid(x_true)
__device__ __forceinline__ float sig_ps(float xs) {
    return __builtin_amdgcn_rcpf(1.0f + __builtin_exp2f(-xs));
}
// xs pre-scaled by 2*log2(e): tanh(x_true) = 2*sigmoid(2x)-1
__device__ __forceinline__ float tanh_ps(float xs) {
    return 2.0f * __builtin_amdgcn_rcpf(1.0f + __builtin_exp2f(-xs)) - 1.0f;
}

// check-first poll: steady state = one agent load, no sleep
__device__ __forceinline__ void flag_wait(const int* f, int v) {
    int x = __hip_atomic_load(f, __ATOMIC_RELAXED, __HIP_MEMORY_SCOPE_AGENT);
    while (x < v) {
        __builtin_amdgcn_s_sleep(8);
        x = __hip_atomic_load(f, __ATOMIC_RELAXED, __HIP_MEMORY_SCOPE_AGENT);
    }
}

// Block = 640 threads = 10 waves:
//   waves 0-7 : compute (MFMA + cell update). NO global memory in steady state
//               -> their barrier vmcnt drain is free.
//   wave  8   : ring producer. Reads h from LDS (64 B/lane), agent-stores the
//               4 KB entry, publishes pout. Its own barrier drain = release.
//   wave  9   : ring consumer (MODE 1) or x stager (MODE 0). Flag poll + loads
//               into depth-4 register queue; commits entry t+1 to Abuf[nxt].
// Ring entry e = 2048 bf16 (4 KB), u64 index i <-> LDS elem offset 4*i
// (A-fragment order, same both sides). Lane i covers u64 [8*lane, 8*lane+8).
template<int MODE, bool CONS, bool PROD, bool WFC>
__device__ __forceinline__ void run_layer_p(
    const float* __restrict__ xin,
    const u64* __restrict__ rin, u64* __restrict__ rout,
    const int* pin_flag, int* cout_flag, const int* cin_flag, int* pout_flag,
    const float* __restrict__ wih, const float* __restrict__ whh,
    const float* __restrict__ bih, const float* __restrict__ bhh,
    unsigned short (* __restrict__ Abuf)[8 * 512],
    float* __restrict__ fcred,
    const int tid, const int wave, const int lane,
    const int n16, const int quad, const int bbase)
{
    constexpr int NKT  = MODE ? 8 : 5;      // K-tiles of 32
    constexpr int KX   = MODE ? 128 : 32;   // padded x-region width
    constexpr int DINL = MODE ? 128 : 6;    // real input features
    constexpr int HB0  = MODE ? 2048 : 512; // h-region start elem

    const bool is_cw = (wave < 8);

    // ---- compute waves: weights -> register B fragments (prescaled) ----
    bf16x8 Wf[4][NKT];
    float  bb[4];
    if (is_cw) {
#pragma unroll
        for (int g = 0; g < 4; ++g) {
            const float sc = (g == 2) ? LOG2E2 : LOG2E;
            const int row = g * 128 + wave * 16 + n16;
            bb[g] = (bih[row] + bhh[row]) * sc;
#pragma unroll
            for (int kt = 0; kt < NKT; ++kt) {
                const int kbase = kt * 32 + quad * 8;
                bf16x8 wv;
#pragma unroll
                for (int j = 0; j < 8; ++j) {
                    const int k = kbase + j;
                    float f;
                    if (k < KX) f = (k < DINL) ? wih[row * DINL + k] : 0.0f;
                    else        f = whh[row * HID + (k - KX)];
                    wv[j] = (short)f2bf(f * sc);
                }
                Wf[g][kt] = wv;
            }
        }
    }

    // ---- prologue: zero h-region (+ MODE0 x pad); I/O wave stages entries ----
    if (tid < 512) {
        u16x4 z = {0, 0, 0, 0};
        *(u16x4*)&Abuf[0][HB0 + tid * 4] = z;
        if constexpr (MODE == 0) {
            const int k = ((tid >> 7) << 3) | (tid & 7);
            if (k >= DINL) { Abuf[0][tid] = 0; Abuf[1][tid] = 0; }
        }
    }

    u64 q0[8], q1[8], q2[8], q3[8];
    int xm0 = 0, xk0 = 0, xm1 = 0, xk1 = 0; bool xe1 = false;
    float xq0a = 0.f, xq0b = 0.f, xq1a = 0.f, xq1b = 0.f;
    if (wave == 9) {
        if constexpr (CONS) {
            flag_wait(pin_flag, 1);
#pragma unroll
            for (int j = 0; j < 8; ++j) {
                u64 v = __hip_atomic_load(rin + lane * 8 + j, __ATOMIC_RELAXED, __HIP_MEMORY_SCOPE_AGENT);
                *(u64*)&Abuf[0][lane * 32 + j * 4] = v;
            }
            flag_wait(pin_flag, 4);
#pragma unroll
            for (int j = 0; j < 8; ++j) {
                q0[j] = __hip_atomic_load(rin + 1 * 512 + lane * 8 + j, __ATOMIC_RELAXED, __HIP_MEMORY_SCOPE_AGENT);
                q1[j] = __hip_atomic_load(rin + 2 * 512 + lane * 8 + j, __ATOMIC_RELAXED, __HIP_MEMORY_SCOPE_AGENT);
                q2[j] = __hip_atomic_load(rin + 3 * 512 + lane * 8 + j, __ATOMIC_RELAXED, __HIP_MEMORY_SCOPE_AGENT);
            }
        } else {
            // x stager: 96 elems (16m x 6k); lane -> e0=lane, e1=64+lane (lane<32)
            xm0 = lane / 6; xk0 = lane % 6;               // e0 = lane (<96 always)
            xe1 = (lane < 32);
            const int e1 = 64 + lane; xm1 = e1 / 6; xk1 = e1 % 6;
            xq0a = xin[((bbase + xm0) * TLEN + 0) * 6 + xk0];
            if (xe1) xq0b = xin[((bbase + xm1) * TLEN + 0) * 6 + xk1];
            Abuf[0][xm0 * 8 + xk0] = f2bf(xq0a);
            if (xe1) Abuf[0][xm1 * 8 + xk1] = f2bf(xq0b);
            xq0a = xin[((bbase + xm0) * TLEN + 1) * 6 + xk0];
            if (xe1) xq0b = xin[((bbase + xm1) * TLEN + 1) * 6 + xk1];
        }
    }

    float cst[4] = {0.f, 0.f, 0.f, 0.f};

    for (int t = 0; t < TLEN; ++t) {
        const int cur = t & 1, nxt = cur ^ 1;
        __syncthreads();   // Abuf[cur] ready; I/O waves' vmem drained

        if (is_cw) {
            // ---- gates = A @ W^T (fp32 accum) ----
            f32x4 acc[4];
#pragma unroll
            for (int g = 0; g < 4; ++g) { f32x4 z = {0.f, 0.f, 0.f, 0.f}; acc[g] = z; }
#pragma unroll
            for (int kt = 0; kt < NKT; ++kt) {
                bf16x8 a = *(const bf16x8*)&Abuf[cur][kt * 512 + lane * 8];
#pragma unroll
                for (int g = 0; g < 4; ++g)
                    acc[g] = __builtin_amdgcn_mfma_f32_16x16x32_bf16(a, Wf[g][kt], acc[g], 0, 0, 0);
            }

            // ---- in-lane LSTM cell update ----
            unsigned short hb[4]; float hf[4];
#pragma unroll
            for (int r = 0; r < 4; ++r) {
                const float iv = sig_ps (acc[0][r] + bb[0]);
                const float fv = sig_ps (acc[1][r] + bb[1]);
                const float gv = tanh_ps(acc[2][r] + bb[2]);
                const float ov = sig_ps (acc[3][r] + bb[3]);
                const float c  = fv * cst[r] + iv * gv;
                cst[r] = c;
                const float h  = ov * tanh_ps(c * LOG2E2);
                hf[r] = h;
                hb[r] = f2bf(h);
            }

            // ---- h -> Abuf[nxt] h-region (A-layout) ----
            {
                const int j  = wave * 16 + n16;
                const int kh = KX + j;
                const int kt = kh >> 5, kk = kh & 31;
                const int eb = kt * 512 + (kk >> 3) * 128 + (kk & 7);
#pragma unroll
                for (int r = 0; r < 4; ++r)
                    Abuf[nxt][eb + (quad * 4 + r) * 8] = hb[r];
            }
            if constexpr (WFC) {
                if (t == TLEN - 1)
#pragma unroll
                    for (int r = 0; r < 4; ++r)
                        fcred[(quad * 4 + r) * HID + wave * 16 + n16] = hf[r];
            }
        } else if (wave == 8) {
            if constexpr (PROD) {
                if (lane == 0 && t >= 2)   // entries <= t-2 drained at my barrier
                    __hip_atomic_store(pout_flag, t - 1, __ATOMIC_RELAXED, __HIP_MEMORY_SCOPE_AGENT);
                if (t >= 1) {
                    const int e = t - 1;
                    if ((e & 3) == 0 && e + 4 > RSLOT) flag_wait(cin_flag, e + 4 - RSLOT);
#pragma unroll
                    for (int j = 0; j < 8; ++j) {
                        u64 hv = *(const u64*)&Abuf[cur][HB0 + lane * 32 + j * 4];
                        __hip_atomic_store(rout + (e & (RSLOT - 1)) * 512 + lane * 8 + j, hv,
                                           __ATOMIC_RELAXED, __HIP_MEMORY_SCOPE_AGENT);
                    }
                }
            }
        } else { // wave 9
            if constexpr (CONS) {
                if (lane == 0)   // entries <= t+3 landed in regs (barrier-drained)
                    __hip_atomic_store(cout_flag, t + 4, __ATOMIC_RELAXED, __HIP_MEMORY_SCOPE_AGENT);
                if (t + 4 < TLEN) {
                    flag_wait(pin_flag, t + 5);
#pragma unroll
                    for (int j = 0; j < 8; ++j)
                        q3[j] = __hip_atomic_load(rin + ((t + 4) & (RSLOT - 1)) * 512 + lane * 8 + j,
                                                  __ATOMIC_RELAXED, __HIP_MEMORY_SCOPE_AGENT);
                }
                if (t + 1 < TLEN) {
#pragma unroll
                    for (int j = 0; j < 8; ++j) {
                        *(u64*)&Abuf[nxt][lane * 32 + j * 4] = q0[j];   // entry t+1
                        q0[j] = q1[j]; q1[j] = q2[j]; q2[j] = q3[j];
                    }
                }
            } else {
                float a1 = 0.f, b1 = 0.f;
                if (t + 2 < TLEN) {
                    a1 = xin[((bbase + xm0) * TLEN + (t + 2)) * 6 + xk0];
                    if (xe1) b1 = xin[((bbase + xm1) * TLEN + (t + 2)) * 6 + xk1];
                }
                if (t + 1 < TLEN) {
                    Abuf[nxt][xm0 * 8 + xk0] = f2bf(xq0a);
                    if (xe1) Abuf[nxt][xm1 * 8 + xk1] = f2bf(xq0b);
                    xq0a = a1; xq0b = b1;
                }
            }
        }
    }

    // ---- producer epilogue: flush entry T-1, final flags ----
    if constexpr (PROD) {
        __syncthreads();   // h(T-1) in Abuf[TLEN&1]; step T-1 stores drained
        if (wave == 8) {
            if (lane == 0)
                __hip_atomic_store(pout_flag, TLEN - 1, __ATOMIC_RELAXED, __HIP_MEMORY_SCOPE_AGENT);
            flag_wait(cin_flag, TLEN - RSLOT);
#pragma unroll
            for (int j = 0; j < 8; ++j) {
                u64 hv = *(const u64*)&Abuf[TLEN & 1][HB0 + lane * 32 + j * 4];
                __hip_atomic_store(rout + ((TLEN - 1) & (RSLOT - 1)) * 512 + lane * 8 + j, hv,
                                   __ATOMIC_RELAXED, __HIP_MEMORY_SCOPE_AGENT);
            }
        }
        __syncthreads();   // wave 8's stores drained at its barrier entry
        if (wave == 8 && lane == 0)
            __hip_atomic_store(pout_flag, TLEN, __ATOMIC_RELAXED, __HIP_MEMORY_SCOPE_AGENT);
    }
}

extern "C" __global__ __launch_bounds__(640, 1)
void lstm3_pipe_kernel(const float* __restrict__ xin,
    const float* __restrict__ wih0, const float* __restrict__ whh0,
    const float* __restrict__ bih0, const float* __restrict__ bhh0,
    const float* __restrict__ wih1, const float* __restrict__ whh1,
    const float* __restrict__ bih1, const float* __restrict__ bhh1,
    const float* __restrict__ wih2, const float* __restrict__ whh2,
    const float* __restrict__ bih2, const float* __restrict__ bhh2,
    const float* __restrict__ fcw, const float* __restrict__ fcb,
    float* __restrict__ out,
    int* __restrict__ flags, u64* __restrict__ ring0, u64* __restrict__ ring1)
{
    __shared__ unsigned short Abuf[2][8 * 512];   // 16 KB
    __shared__ float fcred[16 * HID];             // 8 KB

    const int tid   = threadIdx.x;
    const int wave  = tid >> 6;
    const int lane  = tid & 63;
    const int n16   = lane & 15;
    const int quad  = lane >> 4;
    const int layer = blockIdx.x >> 6;
    const int slice = blockIdx.x & 63;
    const int bbase = slice * 16;

    u64* r0 = ring0 + (size_t)slice * (RSLOT * 512);
    u64* r1 = ring1 + (size_t)slice * (RSLOT * 512);
    // each flag on its own 256 B line
    int* prod0 = flags + (size_t)(0 * 64 + slice) * 64;
    int* prod1 = flags + (size_t)(1 * 64 + slice) * 64;
    int* cons1 = flags + (size_t)(2 * 64 + slice) * 64;
    int* cons2 = flags + (size_t)(3 * 64 + slice) * 64;

    if (layer == 0) {
        run_layer_p<0, false, true, false>(xin, nullptr, r0,
            nullptr, nullptr, cons1, prod0,
            wih0, whh0, bih0, bhh0, Abuf, fcred, tid, wave, lane, n16, quad, bbase);
    } else if (layer == 1) {
        run_layer_p<1, true, true, false>(nullptr, r0, r1,
            prod0, cons1, cons2, prod1,
            wih1, whh1, bih1, bhh1, Abuf, fcred, tid, wave, lane, n16, quad, bbase);
    } else {
        run_layer_p<1, true, false, true>(nullptr, r1, nullptr,
            prod1, cons2, nullptr, nullptr,
            wih2, whh2, bih2, bhh2, Abuf, fcred, tid, wave, lane, n16, quad, bbase);
        __syncthreads();
        if (tid < 16) {
            float s = 0.0f;
#pragma unroll 8
            for (int j = 0; j < HID; ++j) s += fcw[j] * fcred[tid * HID + j];
            out[bbase + tid] = s + fcb[0];
        }
    }
}

extern "C" void kernel_launch(void* const* d_in, const int* in_sizes, int n_in,
                              void* d_out, int out_size, void* d_ws, size_t ws_size,
                              hipStream_t stream) {
    (void)in_sizes; (void)n_in; (void)out_size; (void)ws_size;
    const float* x    = (const float*)d_in[0];
    const float* wih0 = (const float*)d_in[1];
    const float* whh0 = (const float*)d_in[2];
    const float* bih0 = (const float*)d_in[3];
    const float* bhh0 = (const float*)d_in[4];
    const float* wih1 = (const float*)d_in[5];
    const float* whh1 = (const float*)d_in[6];
    const float* bih1 = (const float*)d_in[7];
    const float* bhh1 = (const float*)d_in[8];
    const float* wih2 = (const float*)d_in[9];
    const float* whh2 = (const float*)d_in[10];
    const float* bih2 = (const float*)d_in[11];
    const float* bhh2 = (const float*)d_in[12];
    const float* fcw  = (const float*)d_in[13];
    const float* fcb  = (const float*)d_in[14];
    float* out = (float*)d_out;

    // ws: flags 64 KB (poison-negative = not ready), ring0 8 MB, ring1 8 MB
    int* flags = (int*)d_ws;
    u64* ring0 = (u64*)((char*)d_ws + 65536);
    u64* ring1 = ring0 + (size_t)64 * RSLOT * 512;

    lstm3_pipe_kernel<<<dim3(192), dim3(640), 0, stream>>>(
        x, wih0, whh0, bih0, bhh0, wih1, whh1, bih1, bhh1,
        wih2, whh2, bih2, bhh2, fcw, fcb, out, flags, ring0, ring1);
}

// Round 6
// 897.158 us; speedup vs baseline: 2.4783x; 2.4783x over previous
//
#include <hip/hip_runtime.h>

#define TLEN  512
#define HID   128
#define RSLOT 32   // ring slots per slice (power of 2)

typedef __attribute__((ext_vector_type(8))) short          bf16x8;
typedef __attribute__((ext_vector_type(4))) float          f32x4;
typedef __attribute__((ext_vector_type(4))) unsigned short u16x4;
typedef unsigned long long u64;

#define LOG2E  1.4426950408889634f
#define LOG2E2 2.8853900817779268f

// RNE (cold paths: weights, x staging)
__device__ __forceinline__ unsigned short f2bf(float f) {
    union { float f; unsigned u; } v; v.f = f;
    unsigned r = v.u + 0x7fffu + ((v.u >> 16) & 1u);
    return (unsigned short)(r >> 16);
}
// round-half-up (hot path: h) — 2 ops instead of 5
__device__ __forceinline__ unsigned short f2bf_fast(float f) {
    union { float f; unsigned u; } v; v.f = f;
    return (unsigned short)((v.u + 0x8000u) >> 16);
}

// xs pre-scaled by log2(e): sigmoid(x_true)
__device__ __forceinline__ float sig_ps(float xs) {
    return __builtin_amdgcn_rcpf(1.0f + __builtin_exp2f(-xs));
}
// xs pre-scaled by 2*log2(e): tanh(x_true) = 2*sigmoid(2x)-1
__device__ __forceinline__ float tanh_ps(float xs) {
    return 2.0f * __builtin_amdgcn_rcpf(1.0f + __builtin_exp2f(-xs)) - 1.0f;
}

__device__ __forceinline__ int flag_peek(const int* f) {
    return __hip_atomic_load(f, __ATOMIC_RELAXED, __HIP_MEMORY_SCOPE_AGENT);
}
__device__ __forceinline__ int flag_spin(const int* f, int v) {
    int x = flag_peek(f);
    while (x < v) { __builtin_amdgcn_s_sleep(1); x = flag_peek(f); }
    return x;
}

// One LSTM layer over T steps for a 16-row batch slice. Uniform 8-wave block:
// every wave computes 64 gate columns AND carries 1 ring-load + 1 ring-store
// op per thread (register budget forces uniformity — no wave specialization).
// Flags are pipelined: `pend`/`cpend` hold last step's fire-and-forget flag
// read; the guard spins only when genuinely behind (warmup).
template<int MODE, bool CONS, bool PROD, bool WFC>
__device__ __forceinline__ void run_layer_p(
    const float* __restrict__ xin,
    const u64* __restrict__ rin, u64* __restrict__ rout,
    const int* pin_flag, int* cout_flag, const int* cin_flag, int* pout_flag,
    const float* __restrict__ wih, const float* __restrict__ whh,
    const float* __restrict__ bih, const float* __restrict__ bhh,
    unsigned short (* __restrict__ Abuf)[8 * 512],
    float* __restrict__ fcred,
    const int tid, const int wave, const int lane,
    const int n16, const int quad, const int bbase)
{
    constexpr int NKT  = MODE ? 8 : 5;      // K-tiles of 32
    constexpr int KX   = MODE ? 128 : 32;   // padded x-region width
    constexpr int DINL = MODE ? 128 : 6;    // real input features
    constexpr int HB0  = MODE ? 2048 : 512; // h-region start elem

    // ---- weights -> register/AGPR B fragments (prescaled) ----
    bf16x8 Wf[4][NKT];
    float  bb[4];
#pragma unroll
    for (int g = 0; g < 4; ++g) {
        const float sc = (g == 2) ? LOG2E2 : LOG2E;
        const int row = g * 128 + wave * 16 + n16;
        bb[g] = (bih[row] + bhh[row]) * sc;
#pragma unroll
        for (int kt = 0; kt < NKT; ++kt) {
            const int kbase = kt * 32 + quad * 8;
            bf16x8 wv;
#pragma unroll
            for (int j = 0; j < 8; ++j) {
                const int k = kbase + j;
                float f;
                if (k < KX) f = (k < DINL) ? wih[row * DINL + k] : 0.0f;
                else        f = whh[row * HID + (k - KX)];
                wv[j] = (short)f2bf(f * sc);
            }
            Wf[g][kt] = wv;
        }
    }

    // ---- prologue: zero h-region; stage entry 0 -> LDS, 1..3 -> queue ----
    { u16x4 z = {0, 0, 0, 0}; *(u16x4*)&Abuf[0][HB0 + tid * 4] = z; }
    u64 q0 = 0, q1 = 0, q2 = 0, q3 = 0;
    float pfx0 = 0.0f;
    int pend = 0, cpend = 0;
    if constexpr (CONS) {
        flag_spin(pin_flag, 1);
        u64 v0 = __hip_atomic_load(rin + tid, __ATOMIC_RELAXED, __HIP_MEMORY_SCOPE_AGENT);
        *(u64*)&Abuf[0][tid * 4] = v0;
        pend = flag_spin(pin_flag, 4);
        q0 = __hip_atomic_load(rin + 1 * 512 + tid, __ATOMIC_RELAXED, __HIP_MEMORY_SCOPE_AGENT);
        q1 = __hip_atomic_load(rin + 2 * 512 + tid, __ATOMIC_RELAXED, __HIP_MEMORY_SCOPE_AGENT);
        q2 = __hip_atomic_load(rin + 3 * 512 + tid, __ATOMIC_RELAXED, __HIP_MEMORY_SCOPE_AGENT);
    } else {
        const int m = tid >> 5, k = tid & 31;
        float v = (k < DINL) ? xin[((bbase + m) * TLEN + 0) * DINL + k] : 0.0f;
        Abuf[0][((k >> 3) * 16 + m) * 8 + (k & 7)] = f2bf(v);
        if (k < DINL) pfx0 = xin[((bbase + m) * TLEN + 1) * DINL + k];
    }
    if constexpr (PROD) cpend = -(1 << 30);   // force first real check to spin

    float cst[4] = {0.f, 0.f, 0.f, 0.f};

    for (int t = 0; t < TLEN; ++t) {
        const int cur = t & 1, nxt = cur ^ 1;
        __syncthreads();   // Abuf[cur] ready; all vmem drained (vmcnt(0))

        // ---- publish progress (fire-and-forget) ----
        if (tid == 0) {
            if constexpr (CONS)   // entries <= t+3 landed (drained by barrier)
                __hip_atomic_store(cout_flag, t + 4, __ATOMIC_RELAXED, __HIP_MEMORY_SCOPE_AGENT);
            if constexpr (PROD)   // entries <= t-2 globally visible
                if (t >= 2)
                    __hip_atomic_store(pout_flag, t - 1, __ATOMIC_RELAXED, __HIP_MEMORY_SCOPE_AGENT);
        }

        // ---- ring load of entry t+4 (issued early; gated by LAST step's flag) ----
        if constexpr (CONS) {
            if (t + 4 < TLEN) {
                if (pend < t + 5) pend = flag_spin(pin_flag, t + 5);  // rare
                q3 = __hip_atomic_load(rin + ((t + 4) & (RSLOT - 1)) * 512 + tid,
                                       __ATOMIC_RELAXED, __HIP_MEMORY_SCOPE_AGENT);
                pend = flag_peek(pin_flag);   // deferred refresh, used next step
            }
        }

        // ---- producer: store entry t-1 (h(t-1) in Abuf[cur]) ----
        if constexpr (PROD) {
            if (t >= 1) {
                const int e = t - 1;
                if ((e & 3) == 0 && e + 4 > RSLOT && cpend < e + 4 - RSLOT)
                    cpend = flag_spin(cin_flag, e + 4 - RSLOT);       // rare
                u64 hv = *(const u64*)&Abuf[cur][HB0 + tid * 4];
                __hip_atomic_store(rout + (e & (RSLOT - 1)) * 512 + tid, hv,
                                   __ATOMIC_RELAXED, __HIP_MEMORY_SCOPE_AGENT);
                if ((e & 3) == 1) cpend = flag_peek(cin_flag);        // deferred refresh
            }
        }

        // ---- prefetch x(t+2) (MODE 0) ----
        float pfx1 = 0.0f;
        if constexpr (!CONS) {
            if (t + 2 < TLEN) {
                const int m = tid >> 5, k = tid & 31;
                if (k < DINL) pfx1 = xin[((bbase + m) * TLEN + (t + 2)) * DINL + k];
            }
        }

        // ---- gates = A @ W^T (fp32 accum, bias pre-loaded into acc) ----
        f32x4 acc[4];
#pragma unroll
        for (int g = 0; g < 4; ++g) {
            f32x4 bi = {bb[g], bb[g], bb[g], bb[g]};
            acc[g] = bi;
        }
#pragma unroll
        for (int kt = 0; kt < NKT; ++kt) {
            bf16x8 a = *(const bf16x8*)&Abuf[cur][kt * 512 + lane * 8];
#pragma unroll
            for (int g = 0; g < 4; ++g)
                acc[g] = __builtin_amdgcn_mfma_f32_16x16x32_bf16(a, Wf[g][kt], acc[g], 0, 0, 0);
        }

        // ---- in-lane LSTM cell update ----
        unsigned short hb[4]; float hf[4];
#pragma unroll
        for (int r = 0; r < 4; ++r) {
            const float iv = sig_ps (acc[0][r]);
            const float fv = sig_ps (acc[1][r]);
            const float gv = tanh_ps(acc[2][r]);
            const float ov = sig_ps (acc[3][r]);
            const float c  = fv * cst[r] + iv * gv;
            cst[r] = c;
            const float h  = ov * tanh_ps(c * LOG2E2);
            hf[r] = h;
            hb[r] = f2bf_fast(h);
        }

        // ---- h -> Abuf[nxt] h-region (A-layout, own recurrence) ----
        {
            const int j  = wave * 16 + n16;
            const int kh = KX + j;
            const int kt = kh >> 5, kk = kh & 31;
            const int eb = kt * 512 + (kk >> 3) * 128 + (kk & 7);
#pragma unroll
            for (int r = 0; r < 4; ++r)
                Abuf[nxt][eb + (quad * 4 + r) * 8] = hb[r];
        }
        if constexpr (WFC) {
            if (t == TLEN - 1)
#pragma unroll
                for (int r = 0; r < 4; ++r)
                    fcred[(quad * 4 + r) * HID + wave * 16 + n16] = hf[r];
        }

        // ---- commit next-step x into Abuf[nxt] x-region; shift queue ----
        if (t + 1 < TLEN) {
            if constexpr (CONS) {
                *(u64*)&Abuf[nxt][tid * 4] = q0;   // entry t+1 (loaded 3 steps ago)
                q0 = q1; q1 = q2; q2 = q3;
            } else {
                const int m = tid >> 5, k = tid & 31;
                Abuf[nxt][((k >> 3) * 16 + m) * 8 + (k & 7)] = f2bf(pfx0);
                pfx0 = pfx1;
            }
        }
    }

    // ---- producer epilogue: flush entry T-1, final flags ----
    if constexpr (PROD) {
        __syncthreads();   // h(T-1) in Abuf[TLEN&1]; step T-1 stores drained
        if (tid == 0)
            __hip_atomic_store(pout_flag, TLEN - 1, __ATOMIC_RELAXED, __HIP_MEMORY_SCOPE_AGENT);
        {
            flag_spin(cin_flag, TLEN - RSLOT);
            u64 hv = *(const u64*)&Abuf[TLEN & 1][HB0 + tid * 4];
            __hip_atomic_store(rout + ((TLEN - 1) & (RSLOT - 1)) * 512 + tid, hv,
                               __ATOMIC_RELAXED, __HIP_MEMORY_SCOPE_AGENT);
        }
        __syncthreads();   // drain entry T-1 stores
        if (tid == 0)
            __hip_atomic_store(pout_flag, TLEN, __ATOMIC_RELAXED, __HIP_MEMORY_SCOPE_AGENT);
    }
}

extern "C" __global__ __launch_bounds__(512, 2)
void lstm3_pipe_kernel(const float* __restrict__ xin,
    const float* __restrict__ wih0, const float* __restrict__ whh0,
    const float* __restrict__ bih0, const float* __restrict__ bhh0,
    const float* __restrict__ wih1, const float* __restrict__ whh1,
    const float* __restrict__ bih1, const float* __restrict__ bhh1,
    const float* __restrict__ wih2, const float* __restrict__ whh2,
    const float* __restrict__ bih2, const float* __restrict__ bhh2,
    const float* __restrict__ fcw, const float* __restrict__ fcb,
    float* __restrict__ out,
    int* __restrict__ flags, u64* __restrict__ ring0, u64* __restrict__ ring1)
{
    __shared__ unsigned short Abuf[2][8 * 512];   // 16 KB
    __shared__ float fcred[16 * HID];             // 8 KB

    const int tid   = threadIdx.x;
    const int wave  = tid >> 6;
    const int lane  = tid & 63;
    const int n16   = lane & 15;
    const int quad  = lane >> 4;
    const int layer = blockIdx.x >> 6;
    const int slice = blockIdx.x & 63;
    const int bbase = slice * 16;

    u64* r0 = ring0 + (size_t)slice * (RSLOT * 512);
    u64* r1 = ring1 + (size_t)slice * (RSLOT * 512);
    // each flag on its own 256 B line
    int* prod0 = flags + (size_t)(0 * 64 + slice) * 64;
    int* prod1 = flags + (size_t)(1 * 64 + slice) * 64;
    int* cons1 = flags + (size_t)(2 * 64 + slice) * 64;
    int* cons2 = flags + (size_t)(3 * 64 + slice) * 64;

    if (layer == 0) {
        run_layer_p<0, false, true, false>(xin, nullptr, r0,
            nullptr, nullptr, cons1, prod0,
            wih0, whh0, bih0, bhh0, Abuf, fcred, tid, wave, lane, n16, quad, bbase);
    } else if (layer == 1) {
        run_layer_p<1, true, true, false>(nullptr, r0, r1,
            prod0, cons1, cons2, prod1,
            wih1, whh1, bih1, bhh1, Abuf, fcred, tid, wave, lane, n16, quad, bbase);
    } else {
        run_layer_p<1, true, false, true>(nullptr, r1, nullptr,
            prod1, cons2, nullptr, nullptr,
            wih2, whh2, bih2, bhh2, Abuf, fcred, tid, wave, lane, n16, quad, bbase);
        __syncthreads();
        if (tid < 16) {
            float s = 0.0f;
#pragma unroll 8
            for (int j = 0; j < HID; ++j) s += fcw[j] * fcred[tid * HID + j];
            out[bbase + tid] = s + fcb[0];
        }
    }
}

extern "C" void kernel_launch(void* const* d_in, const int* in_sizes, int n_in,
                              void* d_out, int out_size, void* d_ws, size_t ws_size,
                              hipStream_t stream) {
    (void)in_sizes; (void)n_in; (void)out_size; (void)ws_size;
    const float* x    = (const float*)d_in[0];
    const float* wih0 = (const float*)d_in[1];
    const float* whh0 = (const float*)d_in[2];
    const float* bih0 = (const float*)d_in[3];
    const float* bhh0 = (const float*)d_in[4];
    const float* wih1 = (const float*)d_in[5];
    const float* whh1 = (const float*)d_in[6];
    const float* bih1 = (const float*)d_in[7];
    const float* bhh1 = (const float*)d_in[8];
    const float* wih2 = (const float*)d_in[9];
    const float* whh2 = (const float*)d_in[10];
    const float* bih2 = (const float*)d_in[11];
    const float* bhh2 = (const float*)d_in[12];
    const float* fcw  = (const float*)d_in[13];
    const float* fcb  = (const float*)d_in[14];
    float* out = (float*)d_out;

    // ws: flags 64 KB (poison-negative = not ready), ring0 8 MB, ring1 8 MB
    int* flags = (int*)d_ws;
    u64* ring0 = (u64*)((char*)d_ws + 65536);
    u64* ring1 = ring0 + (size_t)64 * RSLOT * 512;

    lstm3_pipe_kernel<<<dim3(192), dim3(512), 0, stream>>>(
        x, wih0, whh0, bih0, bhh0, wih1, whh1, bih1, bhh1,
        wih2, whh2, bih2, bhh2, fcw, fcb, out, flags, ring0, ring1);
}